// Round 14
// baseline (132.301 us; speedup 1.0000x reference)
//
#include <hip/hip_runtime.h>
#include <hip/hip_bf16.h>
#include <math.h>

// ============================================================================
// MultiHeadAttention: B=2, S=2048, H=1024, NH=16, HD=64
// I/O: fp32 (x, Wq/bq, Wk/bk, Wv/bv), int32 mask; out fp32.
// Internal: bf16 MFMA (16x16x32) with fp32 accum.
// Pipeline: prep(xcast+wtrans) -> qkv_gemm(+maskpack fused) -> attn
//
// Round-14:
//  1) maskpack moved INTO the qkv launch as trailing blocks (bid>=768).
//     mb is only read by attn (next launch) -> safe; the 34MB of BW-bound
//     mask traffic hides under the compute-bound GEMM.
//  2) qkv XCD clustering (T1): f = xcd + 8*(x + 8*sl), slice = sl*8+xcd,
//     y = slice&31, z = slice>>5 (bijective, 768 = 8*8*12). The 8 col-blocks
//     sharing one 256KB A-panel now land on ONE XCD -> panel stays in that
//     XCD's L2 instead of 8 L3 re-fetches.
//  attn unchanged (r12 best: 70.2us, XCD-clustered, r4 body).
//
// MEMORY PLAN:
//   d_ws (25MB used):
//     [0,8M)   Qw  bf16 [b][nh][s][hd]  (pre-scaled by 0.125*log2e)
//     [8M,16M) Kw  bf16 [b][nh][s][hd]
//     [16M,24M)Vtw bf16 [b][nh][hd][s]  (transposed, written by qkv_gemm)
//     [24M,25M)mb  u64 bitmask [b][s][S/64]
//   d_out (16MB fp32) doubles as scratch BEFORE attn (dead until epilogue):
//     [0,8M)   Xb  bf16 [b*s][h]
//     [8M,14M) WT  bf16 3x [n][k] (transposed weights)
// ============================================================================

#define DI __device__ __forceinline__

typedef unsigned short u16;
typedef unsigned int u32;
typedef unsigned long long u64;
typedef __attribute__((ext_vector_type(8))) short bf16x8;
typedef __attribute__((ext_vector_type(4))) float f32x4;

constexpr int BB = 2, SS = 2048, HH = 1024, NHEAD = 16, HDIM = 64;

DI u16 f2bf(float f) {
  __hip_bfloat16 h = __float2bfloat16(f);
  union { __hip_bfloat16 h; u16 u; } c; c.h = h; return c.u;
}

// async global->LDS, 16B per lane; LDS dest = wave-uniform base + lane*16
DI void gload_lds16(const void* g, const void* l) {
  __builtin_amdgcn_global_load_lds(
      (const __attribute__((address_space(1))) u32*)(u64)g,
      (__attribute__((address_space(3))) u32*)(u32)(u64)l,
      16, 0, 0);
}

// ---------------------------------------------------------------------------
// Fused prep: [0,2048) xcast | [2048,2816) wtrans
__global__ void prep(const float* __restrict__ x, u16* __restrict__ xb,
                     const float* __restrict__ Wq, const float* __restrict__ Wk,
                     const float* __restrict__ Wv, u16* __restrict__ WT) {
  __shared__ u16 tile[64][65];
  const int bid = blockIdx.x;
  if (bid < 2048) {
    // xcast: x fp32 -> bf16, 8 elems/thread
    const size_t i = ((size_t)bid * 256 + threadIdx.x) * 8;
    float4 f0 = *(const float4*)(x + i);
    float4 f1 = *(const float4*)(x + i + 4);
    bf16x8 v;
    v[0] = (short)f2bf(f0.x); v[1] = (short)f2bf(f0.y);
    v[2] = (short)f2bf(f0.z); v[3] = (short)f2bf(f0.w);
    v[4] = (short)f2bf(f1.x); v[5] = (short)f2bf(f1.y);
    v[6] = (short)f2bf(f1.z); v[7] = (short)f2bf(f1.w);
    *(bf16x8*)(xb + i) = v;
  } else {
    // wtrans: W fp32 [k][n] -> WT bf16 [n][k], 64x64 tiles
    const int idx = bid - 2048;
    const int z = idx >> 8, rem = idx & 255;
    const int n0 = (rem & 15) * 64, k0 = (rem >> 4) * 64;
    const float* W = (z == 0) ? Wq : (z == 1) ? Wk : Wv;
    u16* Wt = WT + (size_t)z * HH * HH;
    for (int i = threadIdx.x; i < 64 * 64; i += 256) {
      int r = i >> 6, c = i & 63;
      tile[r][c] = f2bf(W[(size_t)(k0 + r) * HH + n0 + c]);
    }
    __syncthreads();
    for (int i = threadIdx.x; i < 64 * 64; i += 256) {
      int r = i >> 6, c = i & 63;
      Wt[(size_t)(n0 + r) * HH + k0 + c] = tile[c][r];
    }
  }
}

// ---------------------------------------------------------------------------
// bid < 768: C[m][n] = X[m][k]*W[k][n] (+bias), XCD-clustered decode.
// bid >= 768: maskpack (int32 {0,1} -> packed bits), hidden under the GEMM.
// GEMM: tile 128x128xBK64, 4 waves each 64x64 (4x4 frags 16x16x32); LDS rows
// 128B, XOR-swizzle byte^=((row&7)<<4) via pre-swizzled global source (G21).
// z==2 (V) writes output TRANSPOSED [bnh][hd][s] via wave-private LDS.
__global__ __launch_bounds__(256) void qkv_gemm(
    const u16* __restrict__ X, const u16* __restrict__ WTall,
    const float* __restrict__ bq, const float* __restrict__ bk,
    const float* __restrict__ bv,
    u16* __restrict__ Qo, u16* __restrict__ Ko, u16* __restrict__ Vo,
    const int* __restrict__ mask, u64* __restrict__ mb) {
  const int bid = blockIdx.x;
  if (bid >= 768) {
    // maskpack: 32768 blocks x 256 threads = 8.4M elements
    const size_t idx = (size_t)(bid - 768) * 256 + threadIdx.x;
    const int v = mask[idx];
    const u64 bal = __ballot(v != 0);
    if ((threadIdx.x & 63) == 0) mb[idx >> 6] = bal;
    return;
  }

  __shared__ alignas(128) u16 As[128 * 64];
  __shared__ alignas(128) u16 Bs[128 * 64];

  // XCD-clustered decode (bijective on [0,768) = 8 xcd x 8 x x 12 sl):
  // all 8 x-blocks sharing an (y,z) A-panel land on one XCD.
  const int xcd = bid & 7;
  const int q = bid >> 3;          // [0,96)
  const int xb = q & 7;            // N tile
  const int sl = q >> 3;           // [0,12)
  const int slice = sl * 8 + xcd;  // [0,96)
  const int y = slice & 31, z = slice >> 5;

  const u16* Wt = WTall + (size_t)z * HH * HH;
  const float* bias = (z == 0) ? bq : (z == 1) ? bk : bv;
  u16* Out = (z == 0) ? Qo : (z == 1) ? Ko : Vo;
  // fold 1/sqrt(HD) AND log2(e) into Q (attn works in exp2 domain)
  const float oscale = (z == 0) ? 0.18033688011112042f : 1.0f;

  const int tid = threadIdx.x;
  const int lane = tid & 63;
  const int w = tid >> 6;
  const int wm = (w >> 1) * 64, wn = (w & 1) * 64;
  const int lr = lane & 15, lkg = lane >> 4;
  const int m0 = y * 128, n0 = xb * 128;

  u32 srow[4], scol[4];
#pragma unroll
  for (int i = 0; i < 4; ++i) {
    u32 f = i * 4096 + w * 1024 + lane * 16;
    u32 g = f ^ (((f >> 7) & 7) << 4);
    srow[i] = g >> 7;
    scol[i] = (g & 127) >> 1;
  }

  u32 aoff[4][2], boff[4][2];
#pragma unroll
  for (int mf = 0; mf < 4; ++mf)
#pragma unroll
    for (int ks = 0; ks < 2; ++ks) {
      int row = wm + mf * 16 + lr;
      aoff[mf][ks] = (u32)((row * 128 + ks * 64 + lkg * 16) ^ ((row & 7) << 4));
      row = wn + mf * 16 + lr;
      boff[mf][ks] = (u32)((row * 128 + ks * 64 + lkg * 16) ^ ((row & 7) << 4));
    }

  f32x4 acc[4][4];
#pragma unroll
  for (int i = 0; i < 4; ++i)
#pragma unroll
    for (int j = 0; j < 4; ++j) acc[i][j] = {0.f, 0.f, 0.f, 0.f};

  const u16* Xb2 = X + (size_t)m0 * HH;
  const u16* Wb = Wt + (size_t)n0 * HH;

  auto stage = [&](int kt) {
    const int k0 = kt * 64;
#pragma unroll
    for (int i = 0; i < 4; ++i) {
      gload_lds16(Xb2 + (size_t)srow[i] * HH + k0 + scol[i],
                  (const char*)As + i * 4096 + w * 1024);
      gload_lds16(Wb + (size_t)srow[i] * HH + k0 + scol[i],
                  (const char*)Bs + i * 4096 + w * 1024);
    }
  };

  stage(0);
  const int NT = HH / 64;  // 16
  for (int kt = 0; kt < NT; ++kt) {
    __syncthreads();
    bf16x8 a[2][4], bfr[2][4];
#pragma unroll
    for (int ks = 0; ks < 2; ++ks)
#pragma unroll
      for (int i = 0; i < 4; ++i) {
        a[ks][i] = *(const bf16x8*)((const char*)As + aoff[i][ks]);
        bfr[ks][i] = *(const bf16x8*)((const char*)Bs + boff[i][ks]);
      }
    __syncthreads();  // (at kt=NT-1 this orders loop-LDS reads vs epilogue)
    if (kt + 1 < NT) stage(kt + 1);
    __builtin_amdgcn_s_setprio(1);
#pragma unroll
    for (int ks = 0; ks < 2; ++ks)
#pragma unroll
      for (int mf = 0; mf < 4; ++mf)
#pragma unroll
        for (int nf = 0; nf < 4; ++nf)
          acc[mf][nf] = __builtin_amdgcn_mfma_f32_16x16x32_bf16(
              a[ks][mf], bfr[ks][nf], acc[mf][nf], 0, 0, 0);
    __builtin_amdgcn_s_setprio(0);
  }

  // epilogue: C/D layout col=lane&15, row=(lane>>4)*4+reg
  if (z < 2) {
#pragma unroll
    for (int mf = 0; mf < 4; ++mf)
#pragma unroll
      for (int nf = 0; nf < 4; ++nf) {
        const int gn = n0 + wn + nf * 16 + lr;
        const float bvv = bias[gn];
        const int nh = gn >> 6, hd = gn & 63;
#pragma unroll
        for (int r = 0; r < 4; ++r) {
          const int gm = m0 + wm + mf * 16 + lkg * 4 + r;
          const int bb = gm >> 11, ss = gm & 2047;
          const float v = (acc[mf][nf][r] + bvv) * oscale;
          Out[(((size_t)bb * NHEAD + nh) * SS + ss) * HDIM + hd] = f2bf(v);
        }
      }
  } else {
    // V: transpose via wave-private LDS (As/Bs dead; kt=NT-1 mid-barrier
    // already ordered all loop reads before we get here).
    char* Lw = (char*)As + w * 8192;
#pragma unroll
    for (int nf = 0; nf < 4; ++nf) {
      const int col = nf * 16 + lr;
      const float bvv = bias[(n0 + wn) + col];
#pragma unroll
      for (int mf = 0; mf < 4; ++mf) {
        union { u16 h[4]; u64 d; } pk;
#pragma unroll
        for (int r = 0; r < 4; ++r) pk.h[r] = f2bf(acc[mf][nf][r] + bvv);
        u32 byte = (u32)(col * 128 + mf * 32 + lkg * 8);
        byte ^= (u32)((col & 7) << 4);  // 16B-granular swizzle (b64-safe)
        *(u64*)(Lw + byte) = pk.d;
      }
    }
    // same-wave LDS ordering is program-order; no barrier needed.
    const int gm0 = m0 + wm;
    const int bb = gm0 >> 11, ss0 = gm0 & 2047;
    const int nh = (n0 + wn) >> 6;
    u16* Vbase = Out + ((size_t)(bb * NHEAD + nh) * HDIM) * SS + ss0;
#pragma unroll
    for (int it = 0; it < 8; ++it) {
      const int idx = it * 64 + lane;
      const int col = idx >> 3, sub = idx & 7;
      const u32 byte = (u32)(col * 128 + sub * 16) ^ (u32)((col & 7) << 4);
      const bf16x8 v = *(const bf16x8*)(Lw + byte);
      *(bf16x8*)(Vbase + (size_t)col * SS + sub * 8) = v;
    }
  }
}

// ---------------------------------------------------------------------------
// Flash attention, swapped-QK^T, no-max softmax. Body = round-4 verified
// structure; XCD-clustered 1-D grid (r12):
//   f = blockIdx.x; xcd = f&7; qt = (f>>3)&31; chi = f>>8;
//   combo c = xcd + 8*chi; nh = c&15; b = c>>4.
__global__ __launch_bounds__(256) void attn(
    const u16* __restrict__ Q, const u16* __restrict__ K,
    const u16* __restrict__ Vt, const u64* __restrict__ mb,
    float* __restrict__ out) {
  __shared__ alignas(128) u16 Ks[64 * 64];
  __shared__ alignas(128) u16 Vs[64 * 64];
  __shared__ alignas(128) u16 Ps[4][16][72];  // per-wave, stride 144B

  // XCD-clustered decode (bijective on [0,1024))
  const int f = blockIdx.x;
  const int xcd = f & 7, qt = (f >> 3) & 31, chi = f >> 8;
  const int c = xcd + 8 * chi;   // combo in [0,32)
  const int nh = c & 15, b = c >> 4;

  const int bnh = b * NHEAD + nh;
  const u16* Qh = Q + (size_t)bnh * SS * HDIM;
  const u16* Kh = K + (size_t)bnh * SS * HDIM;
  const u16* Vh = Vt + (size_t)bnh * HDIM * SS;
  const int q0 = qt * 64;

  const int tid = threadIdx.x, lane = tid & 63, w = tid >> 6;
  const int lr = lane & 15, lkg = lane >> 4;
  const int qrow_lane = q0 + w * 16 + lr;  // this lane's q row (score col)

  // Q fragments (B operand): rows w*16 + lr, k = h*32 + lkg*8 + j
  bf16x8 qf[2];
#pragma unroll
  for (int h = 0; h < 2; ++h)
    qf[h] = *(const bf16x8*)(Qh + (size_t)qrow_lane * HDIM + h * 32 + lkg * 8);

  u32 srow[2], scol[2];
#pragma unroll
  for (int i = 0; i < 2; ++i) {
    u32 fo = i * 4096 + w * 1024 + lane * 16;
    u32 g = fo ^ (((fo >> 7) & 7) << 4);
    srow[i] = g >> 7;
    scol[i] = (g & 127) >> 1;
  }

  auto stage = [&](int t) {
    const int kv0 = t * 64;
#pragma unroll
    for (int i = 0; i < 2; ++i) {
      gload_lds16(Kh + (size_t)(kv0 + srow[i]) * HDIM + scol[i],
                  (const char*)Ks + i * 4096 + w * 1024);
      gload_lds16(Vh + (size_t)srow[i] * SS + kv0 + scol[i],
                  (const char*)Vs + i * 4096 + w * 1024);
    }
  };

  // swizzled read offsets for Ks (row=kv) and Vs (row=hd): same geometry
  u32 koff[4][2];
#pragma unroll
  for (int i = 0; i < 4; ++i)
#pragma unroll
    for (int h = 0; h < 2; ++h) {
      int row = i * 16 + lr;
      koff[i][h] = (u32)((row * 128 + h * 64 + lkg * 16) ^ ((row & 7) << 4));
    }

  // all-ones B fragment for l = P * 1
  bf16x8 ones;
#pragma unroll
  for (int j = 0; j < 8; ++j) ones[j] = (short)0x3F80;

  f32x4 oacc[4];
  f32x4 lacc = {0.f, 0.f, 0.f, 0.f};
#pragma unroll
  for (int n = 0; n < 4; ++n) oacc[n] = {0.f, 0.f, 0.f, 0.f};

  stage(0);
  const int NT = SS / 64;  // 32
  for (int t = 0; t < NT; ++t) {
    __syncthreads();  // K/V tile ready (stage(t) drained here)

    // mask word for this lane's q row; pre-shift so bit (kvb*16+r) applies
    const u64 sh =
        mb[((size_t)b * SS + qrow_lane) * (SS / 64) + t] >> (lkg * 4);
    const u32 w01 = (u32)sh, w23 = (u32)(sh >> 32);

    // swapped QK^T: sacc[kvb] = S[kv][q], kv rows, q cols
    f32x4 sacc[4];
#pragma unroll
    for (int kvb = 0; kvb < 4; ++kvb) sacc[kvb] = {0.f, 0.f, 0.f, 0.f};
    __builtin_amdgcn_s_setprio(1);
#pragma unroll
    for (int kvb = 0; kvb < 4; ++kvb)
#pragma unroll
      for (int h = 0; h < 2; ++h) {
        const bf16x8 kf = *(const bf16x8*)((const char*)Ks + koff[kvb][h]);
        sacc[kvb] = __builtin_amdgcn_mfma_f32_16x16x32_bf16(
            kf, qf[h], sacc[kvb], 0, 0, 0);
      }
    __builtin_amdgcn_s_setprio(0);

    // no-max softmax: p = exp2(s), masked -> s=-14000 -> exp2 -> 0 (f2bf)
#pragma unroll
    for (int kvb = 0; kvb < 4; ++kvb) {
      const u32 word = (kvb < 2) ? w01 : w23;
      const int sb = (kvb & 1) * 16;
      union { u16 h[4]; u64 d; } pk;
#pragma unroll
      for (int r = 0; r < 4; ++r) {
        float s = sacc[kvb][r];
        s = ((word >> (sb + r)) & 1u) ? -14000.0f : s;
        pk.h[r] = f2bf(__builtin_amdgcn_exp2f(s));
      }
      *(u64*)&Ps[w][lr][kvb * 16 + lkg * 4] = pk.d;
    }

    // PV: O[q][hd] += P[q][kv] * V[kv][hd]; l += P * 1
    __builtin_amdgcn_s_setprio(1);
#pragma unroll
    for (int ks = 0; ks < 2; ++ks) {
      const bf16x8 pf = *(const bf16x8*)&Ps[w][lr][ks * 32 + lkg * 8];
#pragma unroll
      for (int n = 0; n < 4; ++n) {
        const bf16x8 vf = *(const bf16x8*)((const char*)Vs + koff[n][ks]);
        oacc[n] = __builtin_amdgcn_mfma_f32_16x16x32_bf16(
            pf, vf, oacc[n], 0, 0, 0);
      }
      lacc = __builtin_amdgcn_mfma_f32_16x16x32_bf16(pf, ones, lacc, 0, 0, 0);
    }
    __builtin_amdgcn_s_setprio(0);

    __syncthreads();  // all waves done with Ks/Vs
    if (t + 1 < NT) stage(t + 1);
  }

  // epilogue: out[b][q][nh*64+hd] fp32; l already in oacc row domain
#pragma unroll
  for (int r = 0; r < 4; ++r) {
    const float rcp = 1.0f / lacc[r];
    const int qrow = q0 + w * 16 + lkg * 4 + r;
#pragma unroll
    for (int n = 0; n < 4; ++n)
      out[((size_t)b * SS + qrow) * HH + nh * HDIM + n * 16 + lr] =
          oacc[n][r] * rcp;
  }
}

// ---------------------------------------------------------------------------
extern "C" void kernel_launch(void* const* d_in, const int* in_sizes, int n_in,
                              void* d_out, int out_size, void* d_ws,
                              size_t ws_size, hipStream_t stream) {
  const float* x = (const float*)d_in[0];
  const int* mask = (const int*)d_in[1];
  const float* Wq = (const float*)d_in[2];
  const float* bq = (const float*)d_in[3];
  const float* Wk = (const float*)d_in[4];
  const float* bk = (const float*)d_in[5];
  const float* Wv = (const float*)d_in[6];
  const float* bv = (const float*)d_in[7];
  float* out = (float*)d_out;

  char* ws = (char*)d_ws;
  const size_t MB = 1024 * 1024;
  // ws: 25MB used
  u16* Qw = (u16*)(ws + 0 * MB);
  u16* Kw = (u16*)(ws + 8 * MB);
  u16* Vtw = (u16*)(ws + 16 * MB);
  u64* mbp = (u64*)(ws + 24 * MB);
  // d_out doubles as pre-attn scratch (fully dead until attn's epilogue)
  u16* Xb = (u16*)d_out;
  u16* WT = (u16*)((char*)d_out + 8 * MB);

  // prep: 2048 xcast + 768 wtrans blocks
  prep<<<dim3(2048 + 768), 256, 0, stream>>>(x, Xb, Wq, Wk, Wv, WT);
  // qkv (768 XCD-clustered GEMM blocks) + maskpack (32768 blocks) fused
  qkv_gemm<<<dim3(768 + 32768), 256, 0, stream>>>(Xb, WT, bq, bk, bv, Qw, Kw,
                                                  Vtw, mask, mbp);
  attn<<<dim3(NHEAD * (SS / 64) * BB), 256, 0, stream>>>(Qw, Kw, Vtw, mbp, out);
}

// Round 15
// 113.422 us; speedup vs baseline: 1.1665x; 1.1665x over previous
//
#include <hip/hip_runtime.h>
#include <hip/hip_bf16.h>
#include <math.h>

// ============================================================================
// MultiHeadAttention: B=2, S=2048, H=1024, NH=16, HD=64
// I/O: fp32 (x, Wq/bq, Wk/bk, Wv/bv), int32 mask; out fp32.
// Internal: bf16 MFMA (16x16x32) with fp32 accum.
// Pipeline: prep(xcast+wtrans+maskpack) -> qkv_gemm -> attn
//
// Round-15: REVERT r14's maskpack-into-qkv fusion (regression 115->132us:
// the kernel's 32KB static LDS is allocated for ALL blocks incl. the 32768
// trivial maskpack blocks -> ~5 blocks/CU for a BW kernel + mask stream
// thrashing the GEMM's L2 panels). Back to r13's 3-way prep (maskpack
// blocks there carry only 8.3KB LDS -> full occupancy; measured fine).
// KEEP r14's single clean lever: qkv XCD-clustered 1-D grid (T1) —
//   f = xcd + 8*(x + 8*sl); slice = sl*8+xcd; y = slice&31; z = slice>>5
// (bijective, 768 = 8*8*12): the 8 col-blocks sharing one 256KB A-panel
// land on ONE XCD. attn unchanged (r12 best, 70.2us).
//
// MEMORY PLAN:
//   d_ws (25MB used):
//     [0,8M)   Qw  bf16 [b][nh][s][hd]  (pre-scaled by 0.125*log2e)
//     [8M,16M) Kw  bf16 [b][nh][s][hd]
//     [16M,24M)Vtw bf16 [b][nh][hd][s]  (transposed, written by qkv_gemm)
//     [24M,25M)mb  u64 bitmask [b][s][S/64]
//   d_out (16MB fp32) doubles as scratch BEFORE attn (dead until epilogue):
//     [0,8M)   Xb  bf16 [b*s][h]
//     [8M,14M) WT  bf16 3x [n][k] (transposed weights)
// ============================================================================

#define DI __device__ __forceinline__

typedef unsigned short u16;
typedef unsigned int u32;
typedef unsigned long long u64;
typedef __attribute__((ext_vector_type(8))) short bf16x8;
typedef __attribute__((ext_vector_type(4))) float f32x4;

constexpr int BB = 2, SS = 2048, HH = 1024, NHEAD = 16, HDIM = 64;

DI u16 f2bf(float f) {
  __hip_bfloat16 h = __float2bfloat16(f);
  union { __hip_bfloat16 h; u16 u; } c; c.h = h; return c.u;
}

// async global->LDS, 16B per lane; LDS dest = wave-uniform base + lane*16
DI void gload_lds16(const void* g, const void* l) {
  __builtin_amdgcn_global_load_lds(
      (const __attribute__((address_space(1))) u32*)(u64)g,
      (__attribute__((address_space(3))) u32*)(u32)(u64)l,
      16, 0, 0);
}

// ---------------------------------------------------------------------------
// Fused prep: [0,2048) xcast | [2048,2816) wtrans | [2816,35584) maskpack
__global__ void prep(const float* __restrict__ x, u16* __restrict__ xb,
                     const float* __restrict__ Wq, const float* __restrict__ Wk,
                     const float* __restrict__ Wv, u16* __restrict__ WT,
                     const int* __restrict__ mask, u64* __restrict__ mb) {
  __shared__ u16 tile[64][65];
  const int bid = blockIdx.x;
  if (bid < 2048) {
    // xcast: x fp32 -> bf16, 8 elems/thread
    const size_t i = ((size_t)bid * 256 + threadIdx.x) * 8;
    float4 f0 = *(const float4*)(x + i);
    float4 f1 = *(const float4*)(x + i + 4);
    bf16x8 v;
    v[0] = (short)f2bf(f0.x); v[1] = (short)f2bf(f0.y);
    v[2] = (short)f2bf(f0.z); v[3] = (short)f2bf(f0.w);
    v[4] = (short)f2bf(f1.x); v[5] = (short)f2bf(f1.y);
    v[6] = (short)f2bf(f1.z); v[7] = (short)f2bf(f1.w);
    *(bf16x8*)(xb + i) = v;
  } else if (bid < 2816) {
    // wtrans: W fp32 [k][n] -> WT bf16 [n][k], 64x64 tiles
    const int idx = bid - 2048;
    const int z = idx >> 8, rem = idx & 255;
    const int n0 = (rem & 15) * 64, k0 = (rem >> 4) * 64;
    const float* W = (z == 0) ? Wq : (z == 1) ? Wk : Wv;
    u16* Wt = WT + (size_t)z * HH * HH;
    for (int i = threadIdx.x; i < 64 * 64; i += 256) {
      int r = i >> 6, c = i & 63;
      tile[r][c] = f2bf(W[(size_t)(k0 + r) * HH + n0 + c]);
    }
    __syncthreads();
    for (int i = threadIdx.x; i < 64 * 64; i += 256) {
      int r = i >> 6, c = i & 63;
      Wt[(size_t)(n0 + r) * HH + k0 + c] = tile[c][r];
    }
  } else {
    // maskpack: int32 {0,1} -> packed bits
    const size_t idx = (size_t)(bid - 2816) * 256 + threadIdx.x;
    const int v = mask[idx];
    const u64 bal = __ballot(v != 0);
    if ((threadIdx.x & 63) == 0) mb[idx >> 6] = bal;
  }
}

// ---------------------------------------------------------------------------
// C[m][n] = X[m][k] * W[k][n] (+bias) for z in {Q,K,V}; X bf16 [4096][1024],
// WT bf16 [n][k]. Tile 128x128xBK64, 4 waves each 64x64 (4x4 frags 16x16x32).
// XCD-clustered 1-D grid. LDS rows 128B; XOR-swizzle byte^=((row&7)<<4) via
// pre-swizzled global source (G21). z==2 (V) writes output TRANSPOSED
// [bnh][hd][s] via wave-private LDS (coalesced dwordx4 stores).
__global__ __launch_bounds__(256) void qkv_gemm(
    const u16* __restrict__ X, const u16* __restrict__ WTall,
    const float* __restrict__ bq, const float* __restrict__ bk,
    const float* __restrict__ bv,
    u16* __restrict__ Qo, u16* __restrict__ Ko, u16* __restrict__ Vo) {
  __shared__ alignas(128) u16 As[128 * 64];
  __shared__ alignas(128) u16 Bs[128 * 64];

  // XCD-clustered decode (bijective on [0,768) = 8 xcd x 8 x x 12 sl):
  // all 8 x-blocks sharing an (y,z) A-panel land on one XCD.
  const int bid = blockIdx.x;
  const int xcd = bid & 7;
  const int q = bid >> 3;          // [0,96)
  const int xb = q & 7;            // N tile
  const int sl = q >> 3;           // [0,12)
  const int slice = sl * 8 + xcd;  // [0,96)
  const int y = slice & 31, z = slice >> 5;

  const u16* Wt = WTall + (size_t)z * HH * HH;
  const float* bias = (z == 0) ? bq : (z == 1) ? bk : bv;
  u16* Out = (z == 0) ? Qo : (z == 1) ? Ko : Vo;
  // fold 1/sqrt(HD) AND log2(e) into Q (attn works in exp2 domain)
  const float oscale = (z == 0) ? 0.18033688011112042f : 1.0f;

  const int tid = threadIdx.x;
  const int lane = tid & 63;
  const int w = tid >> 6;
  const int wm = (w >> 1) * 64, wn = (w & 1) * 64;
  const int lr = lane & 15, lkg = lane >> 4;
  const int m0 = y * 128, n0 = xb * 128;

  u32 srow[4], scol[4];
#pragma unroll
  for (int i = 0; i < 4; ++i) {
    u32 f = i * 4096 + w * 1024 + lane * 16;
    u32 g = f ^ (((f >> 7) & 7) << 4);
    srow[i] = g >> 7;
    scol[i] = (g & 127) >> 1;
  }

  u32 aoff[4][2], boff[4][2];
#pragma unroll
  for (int mf = 0; mf < 4; ++mf)
#pragma unroll
    for (int ks = 0; ks < 2; ++ks) {
      int row = wm + mf * 16 + lr;
      aoff[mf][ks] = (u32)((row * 128 + ks * 64 + lkg * 16) ^ ((row & 7) << 4));
      row = wn + mf * 16 + lr;
      boff[mf][ks] = (u32)((row * 128 + ks * 64 + lkg * 16) ^ ((row & 7) << 4));
    }

  f32x4 acc[4][4];
#pragma unroll
  for (int i = 0; i < 4; ++i)
#pragma unroll
    for (int j = 0; j < 4; ++j) acc[i][j] = {0.f, 0.f, 0.f, 0.f};

  const u16* Xb2 = X + (size_t)m0 * HH;
  const u16* Wb = Wt + (size_t)n0 * HH;

  auto stage = [&](int kt) {
    const int k0 = kt * 64;
#pragma unroll
    for (int i = 0; i < 4; ++i) {
      gload_lds16(Xb2 + (size_t)srow[i] * HH + k0 + scol[i],
                  (const char*)As + i * 4096 + w * 1024);
      gload_lds16(Wb + (size_t)srow[i] * HH + k0 + scol[i],
                  (const char*)Bs + i * 4096 + w * 1024);
    }
  };

  stage(0);
  const int NT = HH / 64;  // 16
  for (int kt = 0; kt < NT; ++kt) {
    __syncthreads();
    bf16x8 a[2][4], bfr[2][4];
#pragma unroll
    for (int ks = 0; ks < 2; ++ks)
#pragma unroll
      for (int i = 0; i < 4; ++i) {
        a[ks][i] = *(const bf16x8*)((const char*)As + aoff[i][ks]);
        bfr[ks][i] = *(const bf16x8*)((const char*)Bs + boff[i][ks]);
      }
    __syncthreads();  // (at kt=NT-1 this orders loop-LDS reads vs epilogue)
    if (kt + 1 < NT) stage(kt + 1);
    __builtin_amdgcn_s_setprio(1);
#pragma unroll
    for (int ks = 0; ks < 2; ++ks)
#pragma unroll
      for (int mf = 0; mf < 4; ++mf)
#pragma unroll
        for (int nf = 0; nf < 4; ++nf)
          acc[mf][nf] = __builtin_amdgcn_mfma_f32_16x16x32_bf16(
              a[ks][mf], bfr[ks][nf], acc[mf][nf], 0, 0, 0);
    __builtin_amdgcn_s_setprio(0);
  }

  // epilogue: C/D layout col=lane&15, row=(lane>>4)*4+reg
  if (z < 2) {
#pragma unroll
    for (int mf = 0; mf < 4; ++mf)
#pragma unroll
      for (int nf = 0; nf < 4; ++nf) {
        const int gn = n0 + wn + nf * 16 + lr;
        const float bvv = bias[gn];
        const int nh = gn >> 6, hd = gn & 63;
#pragma unroll
        for (int r = 0; r < 4; ++r) {
          const int gm = m0 + wm + mf * 16 + lkg * 4 + r;
          const int bb = gm >> 11, ss = gm & 2047;
          const float v = (acc[mf][nf][r] + bvv) * oscale;
          Out[(((size_t)bb * NHEAD + nh) * SS + ss) * HDIM + hd] = f2bf(v);
        }
      }
  } else {
    // V: transpose via wave-private LDS (As/Bs dead; kt=NT-1 mid-barrier
    // already ordered all loop reads before we get here).
    char* Lw = (char*)As + w * 8192;
#pragma unroll
    for (int nf = 0; nf < 4; ++nf) {
      const int col = nf * 16 + lr;
      const float bvv = bias[(n0 + wn) + col];
#pragma unroll
      for (int mf = 0; mf < 4; ++mf) {
        union { u16 h[4]; u64 d; } pk;
#pragma unroll
        for (int r = 0; r < 4; ++r) pk.h[r] = f2bf(acc[mf][nf][r] + bvv);
        u32 byte = (u32)(col * 128 + mf * 32 + lkg * 8);
        byte ^= (u32)((col & 7) << 4);  // 16B-granular swizzle (b64-safe)
        *(u64*)(Lw + byte) = pk.d;
      }
    }
    // same-wave LDS ordering is program-order; no barrier needed.
    const int gm0 = m0 + wm;
    const int bb = gm0 >> 11, ss0 = gm0 & 2047;
    const int nh = (n0 + wn) >> 6;
    u16* Vbase = Out + ((size_t)(bb * NHEAD + nh) * HDIM) * SS + ss0;
#pragma unroll
    for (int it = 0; it < 8; ++it) {
      const int idx = it * 64 + lane;
      const int col = idx >> 3, sub = idx & 7;
      const u32 byte = (u32)(col * 128 + sub * 16) ^ (u32)((col & 7) << 4);
      const bf16x8 v = *(const bf16x8*)(Lw + byte);
      *(bf16x8*)(Vbase + (size_t)col * SS + sub * 8) = v;
    }
  }
}

// ---------------------------------------------------------------------------
// Flash attention, swapped-QK^T, no-max softmax. Body = round-4 verified
// structure; XCD-clustered 1-D grid (r12):
//   f = blockIdx.x; xcd = f&7; qt = (f>>3)&31; chi = f>>8;
//   combo c = xcd + 8*chi; nh = c&15; b = c>>4.
__global__ __launch_bounds__(256) void attn(
    const u16* __restrict__ Q, const u16* __restrict__ K,
    const u16* __restrict__ Vt, const u64* __restrict__ mb,
    float* __restrict__ out) {
  __shared__ alignas(128) u16 Ks[64 * 64];
  __shared__ alignas(128) u16 Vs[64 * 64];
  __shared__ alignas(128) u16 Ps[4][16][72];  // per-wave, stride 144B

  // XCD-clustered decode (bijective on [0,1024))
  const int f = blockIdx.x;
  const int xcd = f & 7, qt = (f >> 3) & 31, chi = f >> 8;
  const int c = xcd + 8 * chi;   // combo in [0,32)
  const int nh = c & 15, b = c >> 4;

  const int bnh = b * NHEAD + nh;
  const u16* Qh = Q + (size_t)bnh * SS * HDIM;
  const u16* Kh = K + (size_t)bnh * SS * HDIM;
  const u16* Vh = Vt + (size_t)bnh * HDIM * SS;
  const int q0 = qt * 64;

  const int tid = threadIdx.x, lane = tid & 63, w = tid >> 6;
  const int lr = lane & 15, lkg = lane >> 4;
  const int qrow_lane = q0 + w * 16 + lr;  // this lane's q row (score col)

  // Q fragments (B operand): rows w*16 + lr, k = h*32 + lkg*8 + j
  bf16x8 qf[2];
#pragma unroll
  for (int h = 0; h < 2; ++h)
    qf[h] = *(const bf16x8*)(Qh + (size_t)qrow_lane * HDIM + h * 32 + lkg * 8);

  u32 srow[2], scol[2];
#pragma unroll
  for (int i = 0; i < 2; ++i) {
    u32 fo = i * 4096 + w * 1024 + lane * 16;
    u32 g = fo ^ (((fo >> 7) & 7) << 4);
    srow[i] = g >> 7;
    scol[i] = (g & 127) >> 1;
  }

  auto stage = [&](int t) {
    const int kv0 = t * 64;
#pragma unroll
    for (int i = 0; i < 2; ++i) {
      gload_lds16(Kh + (size_t)(kv0 + srow[i]) * HDIM + scol[i],
                  (const char*)Ks + i * 4096 + w * 1024);
      gload_lds16(Vh + (size_t)srow[i] * SS + kv0 + scol[i],
                  (const char*)Vs + i * 4096 + w * 1024);
    }
  };

  // swizzled read offsets for Ks (row=kv) and Vs (row=hd): same geometry
  u32 koff[4][2];
#pragma unroll
  for (int i = 0; i < 4; ++i)
#pragma unroll
    for (int h = 0; h < 2; ++h) {
      int row = i * 16 + lr;
      koff[i][h] = (u32)((row * 128 + h * 64 + lkg * 16) ^ ((row & 7) << 4));
    }

  // all-ones B fragment for l = P * 1
  bf16x8 ones;
#pragma unroll
  for (int j = 0; j < 8; ++j) ones[j] = (short)0x3F80;

  f32x4 oacc[4];
  f32x4 lacc = {0.f, 0.f, 0.f, 0.f};
#pragma unroll
  for (int n = 0; n < 4; ++n) oacc[n] = {0.f, 0.f, 0.f, 0.f};

  stage(0);
  const int NT = SS / 64;  // 32
  for (int t = 0; t < NT; ++t) {
    __syncthreads();  // K/V tile ready (stage(t) drained here)

    // mask word for this lane's q row; pre-shift so bit (kvb*16+r) applies
    const u64 sh =
        mb[((size_t)b * SS + qrow_lane) * (SS / 64) + t] >> (lkg * 4);
    const u32 w01 = (u32)sh, w23 = (u32)(sh >> 32);

    // swapped QK^T: sacc[kvb] = S[kv][q], kv rows, q cols
    f32x4 sacc[4];
#pragma unroll
    for (int kvb = 0; kvb < 4; ++kvb) sacc[kvb] = {0.f, 0.f, 0.f, 0.f};
    __builtin_amdgcn_s_setprio(1);
#pragma unroll
    for (int kvb = 0; kvb < 4; ++kvb)
#pragma unroll
      for (int h = 0; h < 2; ++h) {
        const bf16x8 kf = *(const bf16x8*)((const char*)Ks + koff[kvb][h]);
        sacc[kvb] = __builtin_amdgcn_mfma_f32_16x16x32_bf16(
            kf, qf[h], sacc[kvb], 0, 0, 0);
      }
    __builtin_amdgcn_s_setprio(0);

    // no-max softmax: p = exp2(s), masked -> s=-14000 -> exp2 -> 0 (f2bf)
#pragma unroll
    for (int kvb = 0; kvb < 4; ++kvb) {
      const u32 word = (kvb < 2) ? w01 : w23;
      const int sb = (kvb & 1) * 16;
      union { u16 h[4]; u64 d; } pk;
#pragma unroll
      for (int r = 0; r < 4; ++r) {
        float s = sacc[kvb][r];
        s = ((word >> (sb + r)) & 1u) ? -14000.0f : s;
        pk.h[r] = f2bf(__builtin_amdgcn_exp2f(s));
      }
      *(u64*)&Ps[w][lr][kvb * 16 + lkg * 4] = pk.d;
    }

    // PV: O[q][hd] += P[q][kv] * V[kv][hd]; l += P * 1
    __builtin_amdgcn_s_setprio(1);
#pragma unroll
    for (int ks = 0; ks < 2; ++ks) {
      const bf16x8 pf = *(const bf16x8*)&Ps[w][lr][ks * 32 + lkg * 8];
#pragma unroll
      for (int n = 0; n < 4; ++n) {
        const bf16x8 vf = *(const bf16x8*)((const char*)Vs + koff[n][ks]);
        oacc[n] = __builtin_amdgcn_mfma_f32_16x16x32_bf16(
            pf, vf, oacc[n], 0, 0, 0);
      }
      lacc = __builtin_amdgcn_mfma_f32_16x16x32_bf16(pf, ones, lacc, 0, 0, 0);
    }
    __builtin_amdgcn_s_setprio(0);

    __syncthreads();  // all waves done with Ks/Vs
    if (t + 1 < NT) stage(t + 1);
  }

  // epilogue: out[b][q][nh*64+hd] fp32; l already in oacc row domain
#pragma unroll
  for (int r = 0; r < 4; ++r) {
    const float rcp = 1.0f / lacc[r];
    const int qrow = q0 + w * 16 + lkg * 4 + r;
#pragma unroll
    for (int n = 0; n < 4; ++n)
      out[((size_t)b * SS + qrow) * HH + nh * HDIM + n * 16 + lr] =
          oacc[n][r] * rcp;
  }
}

// ---------------------------------------------------------------------------
extern "C" void kernel_launch(void* const* d_in, const int* in_sizes, int n_in,
                              void* d_out, int out_size, void* d_ws,
                              size_t ws_size, hipStream_t stream) {
  const float* x = (const float*)d_in[0];
  const int* mask = (const int*)d_in[1];
  const float* Wq = (const float*)d_in[2];
  const float* bq = (const float*)d_in[3];
  const float* Wk = (const float*)d_in[4];
  const float* bk = (const float*)d_in[5];
  const float* Wv = (const float*)d_in[6];
  const float* bv = (const float*)d_in[7];
  float* out = (float*)d_out;

  char* ws = (char*)d_ws;
  const size_t MB = 1024 * 1024;
  // ws: 25MB used
  u16* Qw = (u16*)(ws + 0 * MB);
  u16* Kw = (u16*)(ws + 8 * MB);
  u16* Vtw = (u16*)(ws + 16 * MB);
  u64* mbp = (u64*)(ws + 24 * MB);
  // d_out doubles as pre-attn scratch (fully dead until attn's epilogue)
  u16* Xb = (u16*)d_out;
  u16* WT = (u16*)((char*)d_out + 8 * MB);

  // fused prep: 2048 xcast + 768 wtrans + 32768 maskpack blocks (8.3KB LDS)
  prep<<<dim3(2048 + 768 + 32768), 256, 0, stream>>>(x, Xb, Wq, Wk, Wv, WT,
                                                     mask, mbp);
  // qkv: 768 XCD-clustered GEMM blocks (standalone again)
  qkv_gemm<<<dim3(768), 256, 0, stream>>>(Xb, WT, bq, bk, bv, Qw, Kw, Vtw);
  attn<<<dim3(NHEAD * (SS / 64) * BB), 256, 0, stream>>>(Qw, Kw, Vtw, mbp, out);
}

// Round 16
// 113.108 us; speedup vs baseline: 1.1697x; 1.0028x over previous
//
#include <hip/hip_runtime.h>
#include <hip/hip_bf16.h>
#include <math.h>

// ============================================================================
// MultiHeadAttention: B=2, S=2048, H=1024, NH=16, HD=64
// I/O: fp32 (x, Wq/bq, Wk/bk, Wv/bv), int32 mask; out fp32.
// Internal: bf16 MFMA (16x16x32) with fp32 accum.
// Pipeline: prep(xcast+wtrans+maskpack) -> qkv_gemm -> attn
//
// Round-15: REVERT r14's maskpack-into-qkv fusion (regression 115->132us:
// the kernel's 32KB static LDS is allocated for ALL blocks incl. the 32768
// trivial maskpack blocks -> ~5 blocks/CU for a BW kernel + mask stream
// thrashing the GEMM's L2 panels). Back to r13's 3-way prep (maskpack
// blocks there carry only 8.3KB LDS -> full occupancy; measured fine).
// KEEP r14's single clean lever: qkv XCD-clustered 1-D grid (T1) —
//   f = xcd + 8*(x + 8*sl); slice = sl*8+xcd; y = slice&31; z = slice>>5
// (bijective, 768 = 8*8*12): the 8 col-blocks sharing one 256KB A-panel
// land on ONE XCD. attn unchanged (r12 best, 70.2us).
//
// MEMORY PLAN:
//   d_ws (25MB used):
//     [0,8M)   Qw  bf16 [b][nh][s][hd]  (pre-scaled by 0.125*log2e)
//     [8M,16M) Kw  bf16 [b][nh][s][hd]
//     [16M,24M)Vtw bf16 [b][nh][hd][s]  (transposed, written by qkv_gemm)
//     [24M,25M)mb  u64 bitmask [b][s][S/64]
//   d_out (16MB fp32) doubles as scratch BEFORE attn (dead until epilogue):
//     [0,8M)   Xb  bf16 [b*s][h]
//     [8M,14M) WT  bf16 3x [n][k] (transposed weights)
// ============================================================================

#define DI __device__ __forceinline__

typedef unsigned short u16;
typedef unsigned int u32;
typedef unsigned long long u64;
typedef __attribute__((ext_vector_type(8))) short bf16x8;
typedef __attribute__((ext_vector_type(4))) float f32x4;

constexpr int BB = 2, SS = 2048, HH = 1024, NHEAD = 16, HDIM = 64;

DI u16 f2bf(float f) {
  __hip_bfloat16 h = __float2bfloat16(f);
  union { __hip_bfloat16 h; u16 u; } c; c.h = h; return c.u;
}

// async global->LDS, 16B per lane; LDS dest = wave-uniform base + lane*16
DI void gload_lds16(const void* g, const void* l) {
  __builtin_amdgcn_global_load_lds(
      (const __attribute__((address_space(1))) u32*)(u64)g,
      (__attribute__((address_space(3))) u32*)(u32)(u64)l,
      16, 0, 0);
}

// ---------------------------------------------------------------------------
// Fused prep: [0,2048) xcast | [2048,2816) wtrans | [2816,35584) maskpack
__global__ void prep(const float* __restrict__ x, u16* __restrict__ xb,
                     const float* __restrict__ Wq, const float* __restrict__ Wk,
                     const float* __restrict__ Wv, u16* __restrict__ WT,
                     const int* __restrict__ mask, u64* __restrict__ mb) {
  __shared__ u16 tile[64][65];
  const int bid = blockIdx.x;
  if (bid < 2048) {
    // xcast: x fp32 -> bf16, 8 elems/thread
    const size_t i = ((size_t)bid * 256 + threadIdx.x) * 8;
    float4 f0 = *(const float4*)(x + i);
    float4 f1 = *(const float4*)(x + i + 4);
    bf16x8 v;
    v[0] = (short)f2bf(f0.x); v[1] = (short)f2bf(f0.y);
    v[2] = (short)f2bf(f0.z); v[3] = (short)f2bf(f0.w);
    v[4] = (short)f2bf(f1.x); v[5] = (short)f2bf(f1.y);
    v[6] = (short)f2bf(f1.z); v[7] = (short)f2bf(f1.w);
    *(bf16x8*)(xb + i) = v;
  } else if (bid < 2816) {
    // wtrans: W fp32 [k][n] -> WT bf16 [n][k], 64x64 tiles
    const int idx = bid - 2048;
    const int z = idx >> 8, rem = idx & 255;
    const int n0 = (rem & 15) * 64, k0 = (rem >> 4) * 64;
    const float* W = (z == 0) ? Wq : (z == 1) ? Wk : Wv;
    u16* Wt = WT + (size_t)z * HH * HH;
    for (int i = threadIdx.x; i < 64 * 64; i += 256) {
      int r = i >> 6, c = i & 63;
      tile[r][c] = f2bf(W[(size_t)(k0 + r) * HH + n0 + c]);
    }
    __syncthreads();
    for (int i = threadIdx.x; i < 64 * 64; i += 256) {
      int r = i >> 6, c = i & 63;
      Wt[(size_t)(n0 + r) * HH + k0 + c] = tile[c][r];
    }
  } else {
    // maskpack: int32 {0,1} -> packed bits
    const size_t idx = (size_t)(bid - 2816) * 256 + threadIdx.x;
    const int v = mask[idx];
    const u64 bal = __ballot(v != 0);
    if ((threadIdx.x & 63) == 0) mb[idx >> 6] = bal;
  }
}

// ---------------------------------------------------------------------------
// C[m][n] = X[m][k] * W[k][n] (+bias) for z in {Q,K,V}; X bf16 [4096][1024],
// WT bf16 [n][k]. Tile 128x128xBK64, 4 waves each 64x64 (4x4 frags 16x16x32).
// XCD-clustered 1-D grid. LDS rows 128B; XOR-swizzle byte^=((row&7)<<4) via
// pre-swizzled global source (G21). z==2 (V) writes output TRANSPOSED
// [bnh][hd][s] via wave-private LDS (coalesced dwordx4 stores).
__global__ __launch_bounds__(256) void qkv_gemm(
    const u16* __restrict__ X, const u16* __restrict__ WTall,
    const float* __restrict__ bq, const float* __restrict__ bk,
    const float* __restrict__ bv,
    u16* __restrict__ Qo, u16* __restrict__ Ko, u16* __restrict__ Vo) {
  __shared__ alignas(128) u16 As[128 * 64];
  __shared__ alignas(128) u16 Bs[128 * 64];

  // XCD-clustered decode (bijective on [0,768) = 8 xcd x 8 x x 12 sl):
  // all 8 x-blocks sharing an (y,z) A-panel land on one XCD.
  const int bid = blockIdx.x;
  const int xcd = bid & 7;
  const int q = bid >> 3;          // [0,96)
  const int xb = q & 7;            // N tile
  const int sl = q >> 3;           // [0,12)
  const int slice = sl * 8 + xcd;  // [0,96)
  const int y = slice & 31, z = slice >> 5;

  const u16* Wt = WTall + (size_t)z * HH * HH;
  const float* bias = (z == 0) ? bq : (z == 1) ? bk : bv;
  u16* Out = (z == 0) ? Qo : (z == 1) ? Ko : Vo;
  // fold 1/sqrt(HD) AND log2(e) into Q (attn works in exp2 domain)
  const float oscale = (z == 0) ? 0.18033688011112042f : 1.0f;

  const int tid = threadIdx.x;
  const int lane = tid & 63;
  const int w = tid >> 6;
  const int wm = (w >> 1) * 64, wn = (w & 1) * 64;
  const int lr = lane & 15, lkg = lane >> 4;
  const int m0 = y * 128, n0 = xb * 128;

  u32 srow[4], scol[4];
#pragma unroll
  for (int i = 0; i < 4; ++i) {
    u32 f = i * 4096 + w * 1024 + lane * 16;
    u32 g = f ^ (((f >> 7) & 7) << 4);
    srow[i] = g >> 7;
    scol[i] = (g & 127) >> 1;
  }

  u32 aoff[4][2], boff[4][2];
#pragma unroll
  for (int mf = 0; mf < 4; ++mf)
#pragma unroll
    for (int ks = 0; ks < 2; ++ks) {
      int row = wm + mf * 16 + lr;
      aoff[mf][ks] = (u32)((row * 128 + ks * 64 + lkg * 16) ^ ((row & 7) << 4));
      row = wn + mf * 16 + lr;
      boff[mf][ks] = (u32)((row * 128 + ks * 64 + lkg * 16) ^ ((row & 7) << 4));
    }

  f32x4 acc[4][4];
#pragma unroll
  for (int i = 0; i < 4; ++i)
#pragma unroll
    for (int j = 0; j < 4; ++j) acc[i][j] = {0.f, 0.f, 0.f, 0.f};

  const u16* Xb2 = X + (size_t)m0 * HH;
  const u16* Wb = Wt + (size_t)n0 * HH;

  auto stage = [&](int kt) {
    const int k0 = kt * 64;
#pragma unroll
    for (int i = 0; i < 4; ++i) {
      gload_lds16(Xb2 + (size_t)srow[i] * HH + k0 + scol[i],
                  (const char*)As + i * 4096 + w * 1024);
      gload_lds16(Wb + (size_t)srow[i] * HH + k0 + scol[i],
                  (const char*)Bs + i * 4096 + w * 1024);
    }
  };

  stage(0);
  const int NT = HH / 64;  // 16
  for (int kt = 0; kt < NT; ++kt) {
    __syncthreads();
    bf16x8 a[2][4], bfr[2][4];
#pragma unroll
    for (int ks = 0; ks < 2; ++ks)
#pragma unroll
      for (int i = 0; i < 4; ++i) {
        a[ks][i] = *(const bf16x8*)((const char*)As + aoff[i][ks]);
        bfr[ks][i] = *(const bf16x8*)((const char*)Bs + boff[i][ks]);
      }
    __syncthreads();  // (at kt=NT-1 this orders loop-LDS reads vs epilogue)
    if (kt + 1 < NT) stage(kt + 1);
    __builtin_amdgcn_s_setprio(1);
#pragma unroll
    for (int ks = 0; ks < 2; ++ks)
#pragma unroll
      for (int mf = 0; mf < 4; ++mf)
#pragma unroll
        for (int nf = 0; nf < 4; ++nf)
          acc[mf][nf] = __builtin_amdgcn_mfma_f32_16x16x32_bf16(
              a[ks][mf], bfr[ks][nf], acc[mf][nf], 0, 0, 0);
    __builtin_amdgcn_s_setprio(0);
  }

  // epilogue: C/D layout col=lane&15, row=(lane>>4)*4+reg
  if (z < 2) {
#pragma unroll
    for (int mf = 0; mf < 4; ++mf)
#pragma unroll
      for (int nf = 0; nf < 4; ++nf) {
        const int gn = n0 + wn + nf * 16 + lr;
        const float bvv = bias[gn];
        const int nh = gn >> 6, hd = gn & 63;
#pragma unroll
        for (int r = 0; r < 4; ++r) {
          const int gm = m0 + wm + mf * 16 + lkg * 4 + r;
          const int bb = gm >> 11, ss = gm & 2047;
          const float v = (acc[mf][nf][r] + bvv) * oscale;
          Out[(((size_t)bb * NHEAD + nh) * SS + ss) * HDIM + hd] = f2bf(v);
        }
      }
  } else {
    // V: transpose via wave-private LDS (As/Bs dead; kt=NT-1 mid-barrier
    // already ordered all loop reads before we get here).
    char* Lw = (char*)As + w * 8192;
#pragma unroll
    for (int nf = 0; nf < 4; ++nf) {
      const int col = nf * 16 + lr;
      const float bvv = bias[(n0 + wn) + col];
#pragma unroll
      for (int mf = 0; mf < 4; ++mf) {
        union { u16 h[4]; u64 d; } pk;
#pragma unroll
        for (int r = 0; r < 4; ++r) pk.h[r] = f2bf(acc[mf][nf][r] + bvv);
        u32 byte = (u32)(col * 128 + mf * 32 + lkg * 8);
        byte ^= (u32)((col & 7) << 4);  // 16B-granular swizzle (b64-safe)
        *(u64*)(Lw + byte) = pk.d;
      }
    }
    // same-wave LDS ordering is program-order; no barrier needed.
    const int gm0 = m0 + wm;
    const int bb = gm0 >> 11, ss0 = gm0 & 2047;
    const int nh = (n0 + wn) >> 6;
    u16* Vbase = Out + ((size_t)(bb * NHEAD + nh) * HDIM) * SS + ss0;
#pragma unroll
    for (int it = 0; it < 8; ++it) {
      const int idx = it * 64 + lane;
      const int col = idx >> 3, sub = idx & 7;
      const u32 byte = (u32)(col * 128 + sub * 16) ^ (u32)((col & 7) << 4);
      const bf16x8 v = *(const bf16x8*)(Lw + byte);
      *(bf16x8*)(Vbase + (size_t)col * SS + sub * 8) = v;
    }
  }
}

// ---------------------------------------------------------------------------
// Flash attention, swapped-QK^T, no-max softmax. Body = round-4 verified
// structure; XCD-clustered 1-D grid (r12):
//   f = blockIdx.x; xcd = f&7; qt = (f>>3)&31; chi = f>>8;
//   combo c = xcd + 8*chi; nh = c&15; b = c>>4.
__global__ __launch_bounds__(256) void attn(
    const u16* __restrict__ Q, const u16* __restrict__ K,
    const u16* __restrict__ Vt, const u64* __restrict__ mb,
    float* __restrict__ out) {
  __shared__ alignas(128) u16 Ks[64 * 64];
  __shared__ alignas(128) u16 Vs[64 * 64];
  __shared__ alignas(128) u16 Ps[4][16][72];  // per-wave, stride 144B

  // XCD-clustered decode (bijective on [0,1024))
  const int f = blockIdx.x;
  const int xcd = f & 7, qt = (f >> 3) & 31, chi = f >> 8;
  const int c = xcd + 8 * chi;   // combo in [0,32)
  const int nh = c & 15, b = c >> 4;

  const int bnh = b * NHEAD + nh;
  const u16* Qh = Q + (size_t)bnh * SS * HDIM;
  const u16* Kh = K + (size_t)bnh * SS * HDIM;
  const u16* Vh = Vt + (size_t)bnh * HDIM * SS;
  const int q0 = qt * 64;

  const int tid = threadIdx.x, lane = tid & 63, w = tid >> 6;
  const int lr = lane & 15, lkg = lane >> 4;
  const int qrow_lane = q0 + w * 16 + lr;  // this lane's q row (score col)

  // Q fragments (B operand): rows w*16 + lr, k = h*32 + lkg*8 + j
  bf16x8 qf[2];
#pragma unroll
  for (int h = 0; h < 2; ++h)
    qf[h] = *(const bf16x8*)(Qh + (size_t)qrow_lane * HDIM + h * 32 + lkg * 8);

  u32 srow[2], scol[2];
#pragma unroll
  for (int i = 0; i < 2; ++i) {
    u32 fo = i * 4096 + w * 1024 + lane * 16;
    u32 g = fo ^ (((fo >> 7) & 7) << 4);
    srow[i] = g >> 7;
    scol[i] = (g & 127) >> 1;
  }

  auto stage = [&](int t) {
    const int kv0 = t * 64;
#pragma unroll
    for (int i = 0; i < 2; ++i) {
      gload_lds16(Kh + (size_t)(kv0 + srow[i]) * HDIM + scol[i],
                  (const char*)Ks + i * 4096 + w * 1024);
      gload_lds16(Vh + (size_t)srow[i] * SS + kv0 + scol[i],
                  (const char*)Vs + i * 4096 + w * 1024);
    }
  };

  // swizzled read offsets for Ks (row=kv) and Vs (row=hd): same geometry
  u32 koff[4][2];
#pragma unroll
  for (int i = 0; i < 4; ++i)
#pragma unroll
    for (int h = 0; h < 2; ++h) {
      int row = i * 16 + lr;
      koff[i][h] = (u32)((row * 128 + h * 64 + lkg * 16) ^ ((row & 7) << 4));
    }

  // all-ones B fragment for l = P * 1
  bf16x8 ones;
#pragma unroll
  for (int j = 0; j < 8; ++j) ones[j] = (short)0x3F80;

  f32x4 oacc[4];
  f32x4 lacc = {0.f, 0.f, 0.f, 0.f};
#pragma unroll
  for (int n = 0; n < 4; ++n) oacc[n] = {0.f, 0.f, 0.f, 0.f};

  stage(0);
  const int NT = SS / 64;  // 32
  for (int t = 0; t < NT; ++t) {
    __syncthreads();  // K/V tile ready (stage(t) drained here)

    // mask word for this lane's q row; pre-shift so bit (kvb*16+r) applies
    const u64 sh =
        mb[((size_t)b * SS + qrow_lane) * (SS / 64) + t] >> (lkg * 4);
    const u32 w01 = (u32)sh, w23 = (u32)(sh >> 32);

    // swapped QK^T: sacc[kvb] = S[kv][q], kv rows, q cols
    f32x4 sacc[4];
#pragma unroll
    for (int kvb = 0; kvb < 4; ++kvb) sacc[kvb] = {0.f, 0.f, 0.f, 0.f};
    __builtin_amdgcn_s_setprio(1);
#pragma unroll
    for (int kvb = 0; kvb < 4; ++kvb)
#pragma unroll
      for (int h = 0; h < 2; ++h) {
        const bf16x8 kf = *(const bf16x8*)((const char*)Ks + koff[kvb][h]);
        sacc[kvb] = __builtin_amdgcn_mfma_f32_16x16x32_bf16(
            kf, qf[h], sacc[kvb], 0, 0, 0);
      }
    __builtin_amdgcn_s_setprio(0);

    // no-max softmax: p = exp2(s), masked -> s=-14000 -> exp2 -> 0 (f2bf)
#pragma unroll
    for (int kvb = 0; kvb < 4; ++kvb) {
      const u32 word = (kvb < 2) ? w01 : w23;
      const int sb = (kvb & 1) * 16;
      union { u16 h[4]; u64 d; } pk;
#pragma unroll
      for (int r = 0; r < 4; ++r) {
        float s = sacc[kvb][r];
        s = ((word >> (sb + r)) & 1u) ? -14000.0f : s;
        pk.h[r] = f2bf(__builtin_amdgcn_exp2f(s));
      }
      *(u64*)&Ps[w][lr][kvb * 16 + lkg * 4] = pk.d;
    }

    // PV: O[q][hd] += P[q][kv] * V[kv][hd]; l += P * 1
    __builtin_amdgcn_s_setprio(1);
#pragma unroll
    for (int ks = 0; ks < 2; ++ks) {
      const bf16x8 pf = *(const bf16x8*)&Ps[w][lr][ks * 32 + lkg * 8];
#pragma unroll
      for (int n = 0; n < 4; ++n) {
        const bf16x8 vf = *(const bf16x8*)((const char*)Vs + koff[n][ks]);
        oacc[n] = __builtin_amdgcn_mfma_f32_16x16x32_bf16(
            pf, vf, oacc[n], 0, 0, 0);
      }
      lacc = __builtin_amdgcn_mfma_f32_16x16x32_bf16(pf, ones, lacc, 0, 0, 0);
    }
    __builtin_amdgcn_s_setprio(0);

    __syncthreads();  // all waves done with Ks/Vs
    if (t + 1 < NT) stage(t + 1);
  }

  // epilogue: out[b][q][nh*64+hd] fp32; l already in oacc row domain
#pragma unroll
  for (int r = 0; r < 4; ++r) {
    const float rcp = 1.0f / lacc[r];
    const int qrow = q0 + w * 16 + lkg * 4 + r;
#pragma unroll
    for (int n = 0; n < 4; ++n)
      out[((size_t)b * SS + qrow) * HH + nh * HDIM + n * 16 + lr] =
          oacc[n][r] * rcp;
  }
}

// ---------------------------------------------------------------------------
extern "C" void kernel_launch(void* const* d_in, const int* in_sizes, int n_in,
                              void* d_out, int out_size, void* d_ws,
                              size_t ws_size, hipStream_t stream) {
  const float* x = (const float*)d_in[0];
  const int* mask = (const int*)d_in[1];
  const float* Wq = (const float*)d_in[2];
  const float* bq = (const float*)d_in[3];
  const float* Wk = (const float*)d_in[4];
  const float* bk = (const float*)d_in[5];
  const float* Wv = (const float*)d_in[6];
  const float* bv = (const float*)d_in[7];
  float* out = (float*)d_out;

  char* ws = (char*)d_ws;
  const size_t MB = 1024 * 1024;
  // ws: 25MB used
  u16* Qw = (u16*)(ws + 0 * MB);
  u16* Kw = (u16*)(ws + 8 * MB);
  u16* Vtw = (u16*)(ws + 16 * MB);
  u64* mbp = (u64*)(ws + 24 * MB);
  // d_out doubles as pre-attn scratch (fully dead until attn's epilogue)
  u16* Xb = (u16*)d_out;
  u16* WT = (u16*)((char*)d_out + 8 * MB);

  // fused prep: 2048 xcast + 768 wtrans + 32768 maskpack blocks (8.3KB LDS)
  prep<<<dim3(2048 + 768 + 32768), 256, 0, stream>>>(x, Xb, Wq, Wk, Wv, WT,
                                                     mask, mbp);
  // qkv: 768 XCD-clustered GEMM blocks (standalone again)
  qkv_gemm<<<dim3(768), 256, 0, stream>>>(Xb, WT, bq, bk, bv, Qw, Kw, Vtw);
  attn<<<dim3(NHEAD * (SS / 64) * BB), 256, 0, stream>>>(Qw, Kw, Vtw, mbp, out);
}